// Round 14
// baseline (172.980 us; speedup 1.0000x reference)
//
#include <hip/hip_runtime.h>

#define D 256
#define VOCAB 4096
#define NTOT 16384      // 16 * 32 * 32
#define N_OUT0 4194304  // 16*256*32*32

typedef _Float16 half8 __attribute__((ext_vector_type(8)));
typedef float f32x4 __attribute__((ext_vector_type(4)));
typedef unsigned long long u64;

__device__ __forceinline__ u64 pack_key(float d, int v) {
    unsigned u = __float_as_uint(d);
    u ^= ((unsigned)((int)u >> 31)) | 0x80000000u;  // monotonic float->uint
    return ((u64)u << 32) | (unsigned)v;
}

// ---------------- fused pack (hi-only) + hsq + esq/e2max prep ----------------
// blocks 0..511: pack A (hi) + hsq partials (ht REMOVED: refine reads h directly —
//   read-only transform, bitwise-identical keys); 512..767: pack B (hi);
// 768..831: esq + e2maxp partials (+ out2 zero at 768)
// Apk (halfs): [bm 64][w 8][q 4][r 256][j 8]   window = 8192 halfs
// Bpk (halfs): [bn 32][w 8][q 4][r 128][j 8]   window = 4096 halfs
__global__ __launch_bounds__(256) void k_pack(const float* __restrict__ h,
                                              const float* __restrict__ emb,
                                              _Float16* __restrict__ Apk,
                                              _Float16* __restrict__ Bpk,
                                              float* __restrict__ hsqp,
                                              float* __restrict__ esq,
                                              float* __restrict__ e2maxp,
                                              float* __restrict__ out2) {
    __shared__ float S[8192];
    const int tid = threadIdx.x;
    const int bid = blockIdx.x;
    if (bid < 512) {
        const int bm = bid >> 3, w = bid & 7;
        const int b = bm >> 2, p0 = (bm & 3) * 256;
        const float* src = h + ((size_t)b << 18) + p0;
#pragma unroll 4
        for (int cl = 0; cl < 32; ++cl)
            S[cl * 256 + tid] = src[(size_t)(w * 32 + cl) << 10 | (unsigned)tid];
        __syncthreads();
        float sq = 0.0f;
#pragma unroll
        for (int cl = 0; cl < 32; ++cl) {
            float t = S[cl * 256 + tid];
            sq = fmaf(t, t, sq);
        }
        hsqp[(size_t)(bm * 8 + w) * 256 + tid] = sq;
        _Float16* dstT = Apk + (size_t)bm * 65536 + (size_t)w * 8192;
#pragma unroll
        for (int i = 0; i < 4; ++i) {  // q = i, r = tid
            alignas(16) _Float16 hi[8];
#pragma unroll
            for (int j = 0; j < 8; ++j) hi[j] = (_Float16)S[(i * 8 + j) * 256 + tid];
            *(half8*)(dstT + i * 2048 + tid * 8) = *(half8*)hi;
        }
    } else if (bid < 768) {
        const int bid2 = bid - 512;
        const int bn = bid2 >> 3, w = bid2 & 7;
        const int v0 = bn * 128;
#pragma unroll 4
        for (int i = 0; i < 16; ++i) {
            int flat = i * 256 + tid;
            int r = flat >> 5, cl = flat & 31;
            S[cl * 129 + r] = emb[(size_t)(v0 + r) * D + w * 32 + cl];
        }
        __syncthreads();
        _Float16* dstT = Bpk + (size_t)bn * 32768 + (size_t)w * 4096;
#pragma unroll
        for (int i = 0; i < 2; ++i) {
            int s = i * 256 + tid;
            int q = s >> 7, r = s & 127;
            alignas(16) _Float16 hi[8];
#pragma unroll
            for (int j = 0; j < 8; ++j) hi[j] = (_Float16)S[(q * 8 + j) * 129 + r];
            *(half8*)(dstT + q * 1024 + r * 8) = *(half8*)hi;
        }
    } else {
        __shared__ float sm[4];
        const int pid = bid - 768;  // 0..63
        const int lane = tid & 63, wv = tid >> 6;
        const int v0 = pid * 64;
        float lmax = 0.0f;
#pragma unroll 4
        for (int i = 0; i < 16; ++i) {
            int v = v0 + i * 4 + wv;
            float4 e = *(const float4*)(emb + (size_t)v * D + lane * 4);
            float s = e.x * e.x + e.y * e.y + e.z * e.z + e.w * e.w;
#pragma unroll
            for (int m = 32; m >= 1; m >>= 1) s += __shfl_xor(s, m, 64);
            if (lane == 0) esq[v] = s;
            lmax = fmaxf(lmax, s);
        }
        if (lane == 0) sm[wv] = lmax;
        __syncthreads();
        if (tid == 0) {
            e2maxp[pid] = fmaxf(fmaxf(sm[0], sm[1]), fmaxf(sm[2], sm[3]));
            if (pid == 0) out2[0] = 0.0f;
        }
    }
}

// ---------------- distance GEMM (LDS-free K-loop, 128x64 wave tile) + f32 embed top-2 ----------------
// Round-14 retile: wave tile 64x64 -> 128x64 (8 A-frags x 4 B-frags, 32 MFMA / 12
// loads = 2.67 MFMA/load vs 2.0), block 256m x 128n (4 waves as 2m x 2n), grid 2048.
// L2 traffic 1GB -> 768MB (-25%). acc = 8x4 f32x4 (128/lane); launch_bounds(256,2).
// Epilogue: embedded-index f32 top-2 (proven r12/r13); t2 grows to [256][16] = 32KB.
__global__ __launch_bounds__(256, 2) void k_gemm(const _Float16* __restrict__ Apk,
                                                 const _Float16* __restrict__ Bpk,
                                                 const float* __restrict__ esq,
                                                 float2* __restrict__ keys2) {
    __shared__ float2 t2[4096];  // [256 rows][16 j (xor row&7)] = 32KB

    const int tid = threadIdx.x;
    const int bid = blockIdx.x;
    // XCD-chunked bijective swizzle (2048 % 8 == 0); bn fastest for A-panel L2 reuse
    const int swz = (bid & 7) * 256 + (bid >> 3);
    const int bm = swz >> 5, bn = swz & 31;   // bm 0..63 (full 256-row panels), bn 0..31
    const int m0 = bm * 256, n0 = bn * 128;

    const int wv = tid >> 6, l = tid & 63;
    const int wm = wv & 1, wn = wv >> 1;      // 2m x 2n waves; wave tile 128m x 64n
    const int quad = l >> 4, j16 = l & 15;

    const _Float16* aP = Apk + (size_t)bm * 65536 + quad * 2048 + (wm * 128 + j16) * 8;
    const _Float16* bP = Bpk + (size_t)bn * 32768 + quad * 1024 + (wn * 64 + j16) * 8;

    f32x4 acc[8][4];
#pragma unroll
    for (int i = 0; i < 8; ++i)
#pragma unroll
        for (int j = 0; j < 4; ++j) acc[i][j] = (f32x4)0.0f;

    half8 af[8], bf[4], afn[8], bfn[4];
#pragma unroll
    for (int mt = 0; mt < 8; ++mt) af[mt] = *(const half8*)(aP + mt * 128);
#pragma unroll
    for (int nt = 0; nt < 4; ++nt) bf[nt] = *(const half8*)(bP + nt * 128);

#pragma unroll
    for (int w = 0; w < 8; ++w) {
        if (w < 7) {  // prefetch next window's fragments
#pragma unroll
            for (int mt = 0; mt < 8; ++mt)
                afn[mt] = *(const half8*)(aP + (w + 1) * 8192 + mt * 128);
#pragma unroll
            for (int nt = 0; nt < 4; ++nt)
                bfn[nt] = *(const half8*)(bP + (w + 1) * 4096 + nt * 128);
        }
        __builtin_amdgcn_s_setprio(1);
#pragma unroll
        for (int mt = 0; mt < 8; ++mt)
#pragma unroll
            for (int nt = 0; nt < 4; ++nt)
                acc[mt][nt] = __builtin_amdgcn_mfma_f32_16x16x32_f16(af[mt], bf[nt], acc[mt][nt], 0, 0, 0);
        __builtin_amdgcn_s_setprio(0);
#pragma unroll
        for (int mt = 0; mt < 8; ++mt) af[mt] = afn[mt];
#pragma unroll
        for (int nt = 0; nt < 4; ++nt) bf[nt] = bfn[nt];
    }

    // ---- epilogue: embedded-index f32 top-2 via LDS transpose ----
    float es[4];
    unsigned code[4];
#pragma unroll
    for (int nt = 0; nt < 4; ++nt) {
        code[nt] = (unsigned)(wn * 64 + nt * 16 + j16);   // v - bn*128, 7 bits
        es[nt] = esq[n0 + (int)code[nt]];
    }

    float M1 = __builtin_inff(), M2 = __builtin_inff();
#pragma unroll
    for (int pass = 0; pass < 2; ++pass) {
        if (wn == pass) {   // 2 waves (wm=0,1) write all 256 rows x 16 j
#pragma unroll
            for (int mt = 0; mt < 8; ++mt) {
#pragma unroll
                for (int r = 0; r < 4; ++r) {
                    float c[4];
#pragma unroll
                    for (int nt = 0; nt < 4; ++nt) {
                        float dv = es[nt] - 2.0f * acc[mt][nt][r];
                        c[nt] = __uint_as_float((__float_as_uint(dv) & ~127u) | code[nt]);
                    }
                    float p = fminf(c[0], c[1]), q = fmaxf(c[0], c[1]);
                    float rr = fminf(c[2], c[3]), s = fmaxf(c[2], c[3]);
                    float m1 = fminf(p, rr);
                    float m2 = fminf(fmaxf(p, rr), fminf(q, s));
                    int row = wm * 128 + mt * 16 + quad * 4 + r;
                    t2[row * 16 + (j16 ^ (row & 7))] = make_float2(m1, m2);
                }
            }
        }
        __syncthreads();
        {   // 256 threads: one row each
            const int row = tid;
#pragma unroll
            for (int j = 0; j < 16; ++j) {
                float2 a = t2[row * 16 + (j ^ (row & 7))];
                float t = fmaxf(M1, a.x);
                M1 = fminf(M1, a.x);
                M2 = fminf(fminf(M2, a.y), t);
            }
        }
        __syncthreads();
    }
    keys2[(size_t)(m0 + tid) * 32 + bn] = make_float2(M1, M2);
}

// ---------------- refine: windowed exact argmin -> out1 (reads h directly) ----------------
// exact dot reads h COLUMN-gather (same elements, same mul/fma/butterfly order as the
// proven exact_key_ht => bitwise-identical keys; ht buffer eliminated — read-only change).
__device__ __forceinline__ u64 exact_key_col(const float* __restrict__ h,
                                             const float* __restrict__ emb,
                                             const float* __restrict__ esq,
                                             int rg, int v, int lane) {
    const float* hB = h + (((size_t)(rg >> 10)) << 18) + (rg & 1023);
    const float4 e4 = *(const float4*)(emb + (size_t)v * D + lane * 4);
    float p = hB[(size_t)(lane * 4 + 0) << 10] * e4.x;
    p = fmaf(hB[(size_t)(lane * 4 + 1) << 10], e4.y, p);
    p = fmaf(hB[(size_t)(lane * 4 + 2) << 10], e4.z, p);
    p = fmaf(hB[(size_t)(lane * 4 + 3) << 10], e4.w, p);
#pragma unroll
    for (int m = 32; m >= 1; m >>= 1) p += __shfl_xor(p, m, 64);
    return pack_key(esq[v] - 2.0f * p, v);
}

__global__ __launch_bounds__(256) void k_refine(const float* __restrict__ h,
                                                const float* __restrict__ emb,
                                                const float* __restrict__ esq,
                                                const float* __restrict__ hsqp,
                                                const float* __restrict__ e2maxp,
                                                const float* __restrict__ keys2f,
                                                float* __restrict__ out1) {
    __shared__ float sE2;
    const int tid = threadIdx.x;
    const int lane = tid & 63;
    const int w = tid >> 6;
    const int n0 = blockIdx.x * 32;

    if (tid < 64) {
        float m = e2maxp[tid];
#pragma unroll
        for (int s = 32; s >= 1; s >>= 1) m = fmaxf(m, __shfl_xor(m, s, 64));
        if (tid == 0) sE2 = m;
    }
    __syncthreads();
    const float e2m = sE2;

    // wave w owns rows w*8 .. w*8+7; prefetch next row's keys under current reduce
    int rg = n0 + w * 8;
    float key = keys2f[(size_t)rg * 64 + lane];
#pragma unroll 1
    for (int rr = 0; rr < 8; ++rr, ++rg) {
        float keyn = 0.0f;
        if (rr < 7) keyn = keys2f[(size_t)(rg + 1) * 64 + lane];
        float gm = key;
#pragma unroll
        for (int m = 32; m >= 1; m >>= 1) gm = fminf(gm, __shfl_xor(gm, m, 64));
        // sound window: |approx - true| <= B (f16) + ~8e-3 (embed); thr = gm+2B+slack
        float hq = 0.0f;
#pragma unroll
        for (int k = 0; k < 8; ++k) hq += hsqp[(size_t)(rg >> 8) * 2048 + k * 256 + (rg & 255)];
        const float thr = gm + 4.0e-3f * sqrtf(hq * e2m) + 5.0e-2f;
        u64 cmask = __ballot(key <= thr);
        int bidx;
        if (__popcll(cmask) == 1) {
            // fast path: only gmin in-window; every block's unstored (rank>=3) keys
            // >= its slot-2 > thr => gmin's embedded index is the exact argmin.
            u64 own = __ballot(key == gm);
            int L = __ffsll((long long)own) - 1;
            bidx = (L >> 1) * 128 + (int)(__float_as_uint(gm) & 127u);
        } else {
            u64 bestk = ~0ULL;
            u64 rescan = 0;
            u64 cm = cmask;
            while (cm) {
                int L = __ffsll((long long)cm) - 1;
                cm &= cm - 1;
                if (L & 1) {
                    rescan |= 1ull << (L >> 1);
                } else {
                    float kL = __shfl(key, L, 64);
                    int v = (L >> 1) * 128 + (int)(__float_as_uint(kL) & 127u);
                    u64 ek = exact_key_col(h, emb, esq, rg, v, lane);
                    bestk = ek < bestk ? ek : bestk;
                }
            }
            // rare path, LANE-PARALLEL: 64 lanes x 2 candidates, serial f32 dot
            // (h column wave-uniform/broadcast, emb row per lane), top-2 wave reduce,
            // exact re-eval of the 2 survivors (shared exact rounding).
            while (rescan) {
                int bnr = __ffsll((long long)rescan) - 1;
                rescan &= rescan - 1;
                const float* hB = h + (((size_t)(rg >> 10)) << 18) + (rg & 1023);
                u64 k0 = ~0ULL, k1 = ~0ULL;
#pragma unroll
                for (int c = 0; c < 2; ++c) {
                    int v = bnr * 128 + c * 64 + lane;
                    float p = 0.0f;
#pragma unroll 8
                    for (int d = 0; d < D; ++d)
                        p = fmaf(hB[(size_t)d << 10], emb[(size_t)v * D + d], p);
                    u64 kc = pack_key(esq[v] - 2.0f * p, v);
                    if (c == 0) k0 = kc; else k1 = kc;
                }
                u64 m1 = k0 < k1 ? k0 : k1, m2 = k0 < k1 ? k1 : k0;
#pragma unroll
                for (int m = 32; m >= 1; m >>= 1) {
                    u64 o1 = __shfl_xor(m1, m, 64), o2 = __shfl_xor(m2, m, 64);
                    u64 hi = m1 > o1 ? m1 : o1;
                    m1 = m1 < o1 ? m1 : o1;
                    u64 lo2 = m2 < o2 ? m2 : o2;
                    m2 = hi < lo2 ? hi : lo2;
                }
                u64 e1 = exact_key_col(h, emb, esq, rg, (int)(m1 & 0xFFFFFFFFu), lane);
                u64 e2 = exact_key_col(h, emb, esq, rg, (int)(m2 & 0xFFFFFFFFu), lane);
                bestk = e1 < bestk ? e1 : bestk;
                bestk = e2 < bestk ? e2 : bestk;
            }
            bidx = (int)(bestk & 0xFFFFFFFFu);
        }
        if (lane == 0) out1[rg] = (float)bidx;
        key = keyn;
    }
}

// ---------------- out: gather emb by index, write z_q_st + loss ----------------
__global__ __launch_bounds__(256) void k_out(const float* __restrict__ h,
                                             const float* __restrict__ emb,
                                             const float* __restrict__ out1,
                                             float* __restrict__ out0,
                                             float* __restrict__ out2) {
    __shared__ float zq[32][260];
    __shared__ float wred[4];
    const int tid = threadIdx.x;
    const int lane = tid & 63;
    const int w = tid >> 6;
    const int n0 = blockIdx.x * 32;
    const int b = n0 >> 10;
    const int p0 = n0 & 1023;
#pragma unroll
    for (int rr = 0; rr < 8; ++rr) {
        int r = w * 8 + rr;
        unsigned idx = (unsigned)(int)out1[n0 + r];
        float4 e4 = *(const float4*)(emb + (size_t)idx * D + lane * 4);
        *(float4*)&zq[r][lane * 4] = e4;
    }
    __syncthreads();
    float lsum = 0.0f;
    const size_t base = ((size_t)b * D) << 10;
#pragma unroll 4
    for (int it = 0; it < 32; ++it) {
        int c = it * 8 + (tid >> 5);
        int pp = tid & 31;
        float z = zq[pp][c];
        size_t g = base + ((size_t)c << 10) + p0 + pp;
        float hv = h[g];
        out0[g] = hv + (z - hv);
        float d = hv - z;
        lsum = fmaf(d, d, lsum);
    }
#pragma unroll
    for (int m = 32; m >= 1; m >>= 1) lsum += __shfl_xor(lsum, m, 64);
    if (lane == 0) wred[w] = lsum;
    __syncthreads();
    if (tid == 0)
        atomicAdd(out2, (wred[0] + wred[1] + wred[2] + wred[3]) * (1.0f / (float)N_OUT0));
}

extern "C" void kernel_launch(void* const* d_in, const int* in_sizes, int n_in,
                              void* d_out, int out_size, void* d_ws, size_t ws_size,
                              hipStream_t stream) {
    const float* h = (const float*)d_in[0];
    const float* emb = (const float*)d_in[1];
    float* out0 = (float*)d_out;
    float* out1 = out0 + N_OUT0;
    float* out2 = out1 + NTOT;

    // ws: Apk 8MB | Bpk 2MB | esq 16KB | hsqp 512KB | e2maxp 1KB | keys2f 4MB (~14.5MB)
    char* wsb = (char*)d_ws;
    _Float16* Apk = (_Float16*)wsb;
    _Float16* Bpk = (_Float16*)(wsb + 8388608);
    float* esq = (float*)(wsb + 10485760);
    float* hsqp = (float*)(wsb + 10502144);
    float* e2maxp = (float*)(wsb + 11026432);
    float* keys2f = (float*)(wsb + 11028480);

    hipLaunchKernelGGL(k_pack, dim3(832), dim3(256), 0, stream, h, emb, Apk, Bpk, hsqp, esq, e2maxp, out2);
    hipLaunchKernelGGL(k_gemm, dim3(2048), dim3(256), 0, stream, Apk, Bpk, esq, (float2*)keys2f);
    hipLaunchKernelGGL(k_refine, dim3(NTOT / 32), dim3(256), 0, stream, h, emb, esq, hsqp, e2maxp, keys2f, out1);
    hipLaunchKernelGGL(k_out, dim3(NTOT / 32), dim3(256), 0, stream, h, emb, out1, out0, out2);
}